// Round 5
// baseline (2356.910 us; speedup 1.0000x reference)
//
#include <hip/hip_runtime.h>
#include <math.h>

typedef unsigned short u16;
typedef unsigned int u32;

#define DIM 256
#define HEADS 8
#define ATT_SCALE 0.17677669529663687f

// ---------------- counting sort by dst ----------------
__global__ void k_zero(int* hist, int n){
  int i = blockIdx.x*256 + threadIdx.x;
  if (i < n) hist[i] = 0;
}
__global__ void k_hist(const int* __restrict__ ei, int* __restrict__ hist, int ne){
  int e = blockIdx.x*256 + threadIdx.x;
  if (e < ne) atomicAdd(&hist[ei[e]], 1);
}
__global__ __launch_bounds__(256) void k_scan(const int* __restrict__ hist,
                                              int* __restrict__ rowptr,
                                              int* __restrict__ cursor, int n, int C){
  __shared__ int ssum[256];
  int t = threadIdx.x;
  int loc[64]; int sum = 0;
  for (int j=0;j<C;j++){
    int idx = t*C+j;
    int v = (idx < n) ? hist[idx] : 0;
    loc[j] = sum; sum += v;
  }
  ssum[t] = sum;
  __syncthreads();
  for (int off=1; off<256; off<<=1){
    int v = (t>=off) ? ssum[t-off] : 0;
    __syncthreads();
    ssum[t] += v;
    __syncthreads();
  }
  int base = ssum[t] - sum;  // exclusive prefix of this thread's chunk
  for (int j=0;j<C;j++){
    int idx = t*C+j;
    if (idx <= n){
      int v = base + loc[j];
      rowptr[idx] = v;
      if (idx < n) cursor[idx] = v;
    }
  }
}
__global__ void k_scatter(const int* __restrict__ ei, int* __restrict__ cursor,
                          int* __restrict__ perm, int* __restrict__ ssrc, int ne){
  int e = blockIdx.x*256 + threadIdx.x;
  if (e < ne){
    int d = ei[e];
    int pos = atomicAdd(&cursor[d], 1);
    perm[pos] = e;
    ssrc[pos] = ei[ne + e];
  }
}

// ---------------- qkv[i, p*256+j] = sum_c x[i,c] * Wp[j,c]  (fp32, naive) ----------------
__global__ __launch_bounds__(256) void k_qkv(const float* __restrict__ x,
    const float* __restrict__ Wq, const float* __restrict__ Wk, const float* __restrict__ Wv,
    float* __restrict__ qkv){
  __shared__ float xs[256];
  int i = blockIdx.x, t = threadIdx.x;
  xs[t] = x[(size_t)i*256 + t];
  __syncthreads();
  const float* Ws[3] = {Wq, Wk, Wv};
  #pragma unroll
  for (int p=0;p<3;p++){
    const float* wr = Ws[p] + (size_t)t*256;
    float acc = 0.f;
    for (int c=0;c<256;c++) acc += xs[c]*wr[c];
    qkv[(size_t)i*768 + p*256 + t] = acc;
  }
}

// ---------------- per-node: logits, GELU-MLP, segment softmax ----------------
// g[h][c] = sum_d q[h,d]*Wek[h*32+d,c] computed in LDS per block (fused).
__global__ __launch_bounds__(256) void k_attn(
    const float* __restrict__ qkv, const float* __restrict__ Wek,
    const float* __restrict__ edges, const float* __restrict__ Wexp, const float* __restrict__ Wsq,
    const int* __restrict__ rowptr, const int* __restrict__ perm, const int* __restrict__ ssrc,
    float* __restrict__ zbuf, float* __restrict__ attn_out){
  __shared__ float g_s[8][260];
  __shared__ float q_s[256];
  __shared__ float we_s[128];
  __shared__ float wsq_s[128];
  __shared__ float es_s[8][256];
  __shared__ int  src_s[8];
  __shared__ float z_s[8][8];
  __shared__ float t_s[8][16];
  __shared__ float z2_s[8][8];
  __shared__ float m_s[8];
  __shared__ float s_s[8];
  int i = blockIdx.x, t = threadIdx.x;
  int rs = rowptr[i], re = rowptr[i+1];
  q_s[t] = qkv[(size_t)i*768 + t];
  if (t < 128) we_s[t] = Wexp[t];
  else         wsq_s[t-128] = Wsq[t-128];
  __syncthreads();
  // fused g compute: g_s[h][t] = sum_d q[h*32+d] * Wek[h*32+d][t]
  #pragma unroll
  for (int h=0;h<8;h++){
    float a = 0.f;
    #pragma unroll
    for (int d=0; d<32; d++){
      a += q_s[h*32+d] * Wek[(size_t)(h*32+d)*256 + t];
    }
    g_s[h][t] = a;
  }
  __syncthreads();
  int h = t>>5, s = t&31;
  float mreg = -3.0e38f;
  for (int p0 = rs; p0 < re; p0 += 8){
    int nE = min(8, re-p0);
    for (int ee=0; ee<nE; ee++){
      int er = perm[p0+ee];
      es_s[ee][t] = edges[(size_t)er*256 + t];
    }
    if (t < nE) src_s[t] = ssrc[p0+t];
    __syncthreads();
    for (int ee=0; ee<nE; ee++){
      // edges·g over c = s*8 .. s*8+7 (32 lanes cover 256)
      float partial = 0.f;
      #pragma unroll
      for (int j=0;j<8;j++) partial += es_s[ee][s*8+j]*g_s[h][s*8+j];
      // q·k over d = s (32 lanes cover head_dim 32)
      partial += q_s[h*32+s] * qkv[(size_t)src_s[ee]*768 + 256 + h*32 + s];
      #pragma unroll
      for (int off=16; off>=1; off>>=1)
        partial += __shfl_xor(partial, off, 32);
      if (s == 0) z_s[ee][h] = partial * ATT_SCALE;
    }
    __syncthreads();
    if (t < nE*16){
      int ee = t>>4, j = t&15;
      float u = 0.f;
      #pragma unroll
      for (int hh=0;hh<8;hh++) u += z_s[ee][hh]*we_s[j*8+hh];
      u = 0.5f*u*(1.f + erff(u*0.70710678118654752f));  // exact GELU
      t_s[ee][j] = u;
    }
    __syncthreads();
    if (t < nE*8){
      int ee = t>>3, hh = t&7;
      float z2 = 0.f;
      #pragma unroll
      for (int j=0;j<16;j++) z2 += t_s[ee][j]*wsq_s[hh*16+j];
      z2_s[ee][hh] = z2;
      zbuf[(size_t)(p0+ee)*8 + hh] = z2;
    }
    __syncthreads();
    if (t < 8){
      for (int ee=0;ee<nE;ee++) mreg = fmaxf(mreg, z2_s[ee][t]);
    }
    __syncthreads();
  }
  if (t < 8) m_s[t] = mreg;
  __syncthreads();
  if (t < 8){
    float sr = 0.f;
    for (int p=rs; p<re; p++) sr += expf(zbuf[(size_t)p*8 + t] - m_s[t]);
    s_s[t] = sr;
  }
  __syncthreads();
  {
    int pp = t>>3, hh = t&7;
    for (int p = rs+pp; p < re; p += 32){
      float z = zbuf[(size_t)p*8 + hh];
      float a = expf(z - m_s[hh]) / (s_s[hh] + 1e-16f);
      zbuf[(size_t)p*8 + hh] = a;                      // fp32 attn for k_out
      attn_out[(size_t)perm[p]*8 + hh] = a;            // fp32 attn output
    }
  }
}

// ---------------- per-node: value path + Wev + Wout + bias ----------------
__global__ __launch_bounds__(256) void k_out(
    const float* __restrict__ qkv, const float* __restrict__ edges,
    const float* __restrict__ Wev, const float* __restrict__ Wout, const float* __restrict__ bout,
    const int* __restrict__ rowptr, const int* __restrict__ perm, const int* __restrict__ ssrc,
    const float* __restrict__ zbuf, float* __restrict__ out_d){
  __shared__ float es_s[8][256];
  __shared__ float a_s[8][8];
  __shared__ int  src_s[8];
  __shared__ float t_s[8][260];
  __shared__ float o_s[256];
  int i = blockIdx.x, t = threadIdx.x;
  int rs = rowptr[i], re = rowptr[i+1];
  int hc = t>>5;
  float tacc[8];
  #pragma unroll
  for (int j=0;j<8;j++) tacc[j]=0.f;
  float vacc = 0.f;
  for (int p0=rs; p0<re; p0+=8){
    int nE = min(8, re-p0);
    for (int ee=0; ee<nE; ee++){
      int er = perm[p0+ee];
      es_s[ee][t] = edges[(size_t)er*256 + t];
    }
    if (t < nE*8) a_s[t>>3][t&7] = zbuf[(size_t)(p0 + (t>>3))*8 + (t&7)];
    if (t < nE)   src_s[t] = ssrc[p0+t];
    __syncthreads();
    for (int ee=0; ee<nE; ee++){
      float ef = es_s[ee][t];
      #pragma unroll
      for (int j=0;j<8;j++) tacc[j] += a_s[ee][j]*ef;
      vacc += a_s[ee][hc] * qkv[(size_t)src_s[ee]*768 + 512 + t];
    }
    __syncthreads();
  }
  #pragma unroll
  for (int j=0;j<8;j++) t_s[j][t] = tacc[j];
  __syncthreads();
  float vtot = vacc;
  {
    const float* wp = Wev + (size_t)t*256;
    const float* tp = &t_s[hc][0];
    for (int c=0;c<256;c++) vtot += wp[c]*tp[c];
  }
  o_s[t] = vtot;
  __syncthreads();
  float oacc = bout[t];
  {
    const float* wp = Wout + (size_t)t*256;
    for (int c=0;c<256;c++) oacc += wp[c]*o_s[c];
  }
  out_d[(size_t)i*256 + t] = oacc;
}

extern "C" void kernel_launch(void* const* d_in, const int* in_sizes, int n_in,
                              void* d_out, int out_size, void* d_ws, size_t ws_size,
                              hipStream_t stream){
  const float* x     = (const float*)d_in[0];
  const float* edges = (const float*)d_in[1];
  const int*   ei    = (const int*)d_in[2];
  const float* Wq    = (const float*)d_in[3];
  const float* Wk    = (const float*)d_in[4];
  const float* Wv    = (const float*)d_in[5];
  const float* Wek   = (const float*)d_in[6];
  const float* Wev   = (const float*)d_in[7];
  const float* Wexp  = (const float*)d_in[8];
  const float* Wsq   = (const float*)d_in[9];
  const float* Wout  = (const float*)d_in[10];
  const float* bout  = (const float*)d_in[11];

  // Runtime-derived sizes.
  const int N = in_sizes[0] / DIM;        // x is [N, 256]
  const int E = in_sizes[2] / 2;          // edge_index is [2, E]

  // ws layout, 256B-aligned, fp32 everywhere. ~43.7 MB at N=10000,E=320000.
  char* base = (char*)d_ws;
  size_t off = 0;
  auto align256 = [](size_t v){ return (v + 255) & ~(size_t)255; };
  float* qkv    = (float*)(base + off); off += align256((size_t)N*768*4);
  float* zbuf   = (float*)(base + off); off += align256((size_t)E*8*4);
  int*   rowptr = (int*)(base + off);   off += align256((size_t)(N+1)*4);
  int*   cursor = (int*)(base + off);   off += align256((size_t)N*4);
  int*   hist   = (int*)(base + off);   off += align256((size_t)N*4);
  int*   perm   = (int*)(base + off);   off += align256((size_t)E*4);
  int*   ssrc   = (int*)(base + off);   off += align256((size_t)E*4);

  float* out_d  = (float*)d_out;                  // [N,256] fp32
  float* attn_d = out_d + (size_t)N*DIM;          // [E,8] fp32

  int C = N/256 + 1;                              // per-thread chunk in k_scan
  if (C > 64) C = 64;

  k_zero<<<(N+255)/256, 256, 0, stream>>>(hist, N);
  k_hist<<<(E+255)/256, 256, 0, stream>>>(ei, hist, E);
  k_scan<<<1, 256, 0, stream>>>(hist, rowptr, cursor, N, C);
  k_scatter<<<(E+255)/256, 256, 0, stream>>>(ei, cursor, perm, ssrc, E);
  k_qkv<<<N, 256, 0, stream>>>(x, Wq, Wk, Wv, qkv);
  k_attn<<<N, 256, 0, stream>>>(qkv, Wek, edges, Wexp, Wsq,
                                rowptr, perm, ssrc, zbuf, attn_d);
  k_out<<<N, 256, 0, stream>>>(qkv, edges, Wev, Wout, bout,
                               rowptr, perm, ssrc, zbuf, out_d);
}